// Round 9
// baseline (99.828 us; speedup 1.0000x reference)
//
#include <hip/hip_runtime.h>
#include <hip/hip_cooperative_groups.h>

namespace cg = cooperative_groups;

constexpr int NCLS = 16;
constexpr int NG   = 50;
constexpr int CH   = 21;                 // 5 + NCLS
constexpr float EPSF = 1e-8f;

// ws layout (floats): parts_bg[B*21] at 0; parts_fg[5][B] at B*21.
// All slots written unconditionally every call -> no memset needed.
// Single cooperative kernel: bg blocks + fg blocks -> grid.sync -> block 0 reduces.

__global__ __launch_bounds__(256) void dpsv_coop_kernel(
    const float* __restrict__ in0, const float* __restrict__ in1,
    const float* __restrict__ in2, const float* __restrict__ labels,
    float* __restrict__ parts_bg, float* __restrict__ parts_fg,
    float* __restrict__ out, int B)
{
    const int tid = threadIdx.x;
    const int nbg = B * 21;
    const int wave = tid >> 6;
    const int lane = tid & 63;

    __shared__ float lab[5 * NG];
    __shared__ int   cand[3 * NG];
    __shared__ float red[4][5];

    if (blockIdx.x < (unsigned)nbg) {
        // ======== bg: one float4 of the obj plane per thread ========
        const int b = blockIdx.x / 21;
        const int r = blockIdx.x % 21;

        const float* ptr;
        if (r < 16)      ptr = in0 + ((size_t)(b * CH + 4)) * 16384 + (size_t)(r * 256 + tid) * 4;
        else if (r < 20) ptr = in1 + ((size_t)(b * CH + 4)) * 4096  + (size_t)((r - 16) * 256 + tid) * 4;
        else             ptr = in2 + ((size_t)(b * CH + 4)) * 1024  + (size_t)tid * 4;

        const float4 o = *(const float4*)ptr;
        float v = -(__logf(1.f - o.x + EPSF) + __logf(1.f - o.y + EPSF) +
                    __logf(1.f - o.z + EPSF) + __logf(1.f - o.w + EPSF));

        #pragma unroll
        for (int off = 32; off > 0; off >>= 1)
            v += __shfl_xor(v, off, 64);

        if (lane == 0) red[wave][0] = v;
        __syncthreads();
        if (tid == 0)
            parts_bg[blockIdx.x] = red[0][0] + red[1][0] + red[2][0] + red[3][0];
    } else {
        // ======== fg: threads 0..149 map to (level, g) ========
        const int b = blockIdx.x - nbg;

        if (tid < 5 * NG) lab[tid] = labels[b * 5 * NG + tid];
        if (tid < 3 * NG) cand[tid] = -1;
        __syncthreads();

        const int lv = tid / NG;            // 0..2 for tid<150
        const int g  = tid % NG;

        int xm = -1, ym = -1, found = -1;
        float s = 0.f; int W = 0, HW = 0;
        if (tid < 150) {
            s = (float)(8 << lv);
            const float rr = 0.5f * s;
            W = 128 >> lv; HW = W * W;
            const float gx = lab[g * 5 + 0];
            const float gy = lab[g * 5 + 1];
            const int x0 = (int)floorf(gx / s);
            const int y0 = (int)floorf(gy / s);
            #pragma unroll
            for (int d = -1; d <= 1; ++d) {
                int xc = x0 + d;
                if (xc >= 0 && xc < W) {
                    float cxc = ((float)xc + 0.5f) * s;
                    if (cxc - (gx - rr) > 0.f && gx + rr - cxc > 0.f) xm = xc;
                }
                int yc = y0 + d;
                if (yc >= 0 && yc < W) {
                    float cyc = ((float)yc + 0.5f) * s;
                    if (cyc - (gy - rr) > 0.f && gy + rr - cyc > 0.f) ym = yc;
                }
            }
            if (xm >= 0 && ym >= 0) { found = ym * W + xm; cand[tid] = found; }
        }
        __syncthreads();

        // dedup: anchor matches the LOWEST GT index covering it
        bool fg = (found >= 0);
        if (fg) {
            const int base = lv * NG;
            for (int gp = 0; gp < g; ++gp)
                if (cand[base + gp] == found) { fg = false; break; }
        }

        float vals[5] = {0.f, 0.f, 0.f, 0.f, 0.f};
        if (fg) {
            const float* inp = (lv == 0) ? in0 : (lv == 1) ? in1 : in2;
            const float* chp = inp + ((size_t)b * CH) * HW + found;
            const float obj = chp[4 * HW];
            vals[0] = -1000.f * __logf(obj + EPSF) + __logf(1.f - obj + EPSF);
            float xp = (chp[0]  + (float)xm) * s;
            float yp = (chp[HW] + (float)ym) * s;
            vals[1] = fabsf((lab[g * 5 + 0] - xp) * (1.f / 1024.f));
            vals[2] = fabsf((lab[g * 5 + 1] - yp) * (1.f / 1024.f));
            vals[3] = fabsf(lab[g * 5 + 2] - chp[2 * HW]) * 10.f;
            vals[4] = fabsf(lab[g * 5 + 3] - chp[3 * HW]) * 10.f;
            const int ci = (int)lab[g * 5 + 4];
            float cls_sum = 0.f;
            #pragma unroll
            for (int c = 0; c < NCLS; ++c) {
                float pc  = chp[(5 + c) * HW];
                float lp  = fmaxf(__logf(pc), -100.f);
                float l1p = fmaxf(__logf(1.f - pc), -100.f);
                cls_sum += (c == ci) ? -lp : -l1p;
            }
            vals[0] += 500.f * cls_sum;
        }

        #pragma unroll
        for (int k = 0; k < 5; ++k) {
            float v = vals[k];
            #pragma unroll
            for (int off = 32; off > 0; off >>= 1)
                v += __shfl_xor(v, off, 64);
            vals[k] = v;
        }
        if (lane == 0) {
            #pragma unroll
            for (int k = 0; k < 5; ++k) red[wave][k] = vals[k];
        }
        __syncthreads();
        if (tid < 5)
            parts_fg[tid * B + b] = red[0][tid] + red[1][tid] + red[2][tid] + red[3][tid];
    }

    // ======== grid-wide barrier, then block 0 reduces everything ========
    cg::this_grid().sync();

    if (blockIdx.x == 0) {
        float acc[5] = {0.f, 0.f, 0.f, 0.f, 0.f};
        for (int i = tid; i < nbg; i += 256) acc[0] += parts_bg[i];
        for (int i = tid; i < B;   i += 256) {
            #pragma unroll
            for (int k = 0; k < 5; ++k) acc[k] += parts_fg[k * B + i];
        }
        #pragma unroll
        for (int k = 0; k < 5; ++k) {
            float v = acc[k];
            #pragma unroll
            for (int off = 32; off > 0; off >>= 1)
                v += __shfl_xor(v, off, 64);
            acc[k] = v;
        }
        __syncthreads();             // red[] reuse after bg phase
        if (lane == 0) {
            #pragma unroll
            for (int k = 0; k < 5; ++k) red[wave][k] = acc[k];
        }
        __syncthreads();
        if (tid == 0) {
            float t[5];
            #pragma unroll
            for (int k = 0; k < 5; ++k)
                t[k] = red[0][k] + red[1][k] + red[2][k] + red[3][k];
            out[0] = t[0] + 10000.f * (t[1] + t[2] + t[3] + t[4]);
            out[1] = t[1];
            out[2] = t[2];
            out[3] = t[3];
            out[4] = t[4];
        }
    }
}

extern "C" void kernel_launch(void* const* d_in, const int* in_sizes, int n_in,
                              void* d_out, int out_size, void* d_ws, size_t ws_size,
                              hipStream_t stream) {
    const float* in0    = (const float*)d_in[0];
    const float* in1    = (const float*)d_in[1];
    const float* in2    = (const float*)d_in[2];
    const float* labels = (const float*)d_in[3];
    float* out = (float*)d_out;
    float* ws  = (float*)d_ws;

    int B   = in_sizes[3] / (5 * NG);        // 32
    int nbg = B * 21;                        // 672 bg partials
    float* parts_bg = ws;
    float* parts_fg = ws + nbg;              // 5*B floats

    void* args[] = { (void*)&in0, (void*)&in1, (void*)&in2, (void*)&labels,
                     (void*)&parts_bg, (void*)&parts_fg, (void*)&out, (void*)&B };
    hipLaunchCooperativeKernel((const void*)dpsv_coop_kernel,
                               dim3(nbg + B), dim3(256), args, 0, stream);
}

// Round 10
// 16.181 us; speedup vs baseline: 6.1693x; 6.1693x over previous
//
#include <hip/hip_runtime.h>

constexpr int NCLS = 16;
constexpr int NG   = 50;
constexpr int CH   = 21;                 // 5 + NCLS
constexpr float EPSF = 1e-8f;

// ws layout (floats): parts_bg[B*21] at 0; parts_fg[5][B] at B*21.
// All slots written unconditionally every call -> no memset needed.

// ---------------- fused bg + fg ----------------
// grid = B*21 + B blocks.
//   blocks [0, B*21): bg — sum of -log(1-obj+eps) over all anchors' obj plane.
//   blocks [B*21, B*21+B): fg — GT-centric candidates + fg corrections (1 block/batch).
__global__ __launch_bounds__(256) void dpsv_fused_kernel(
    const float* __restrict__ in0, const float* __restrict__ in1,
    const float* __restrict__ in2, const float* __restrict__ labels,
    float* __restrict__ parts_bg, float* __restrict__ parts_fg, int B)
{
    const int tid = threadIdx.x;
    const int nbg = B * 21;

    if (blockIdx.x < (unsigned)nbg) {
        // ======== bg part: one float4 of the obj plane per thread ========
        const int b = blockIdx.x / 21;
        const int r = blockIdx.x % 21;

        const float* ptr;
        if (r < 16)      ptr = in0 + ((size_t)(b * CH + 4)) * 16384 + (size_t)(r * 256 + tid) * 4;
        else if (r < 20) ptr = in1 + ((size_t)(b * CH + 4)) * 4096  + (size_t)((r - 16) * 256 + tid) * 4;
        else             ptr = in2 + ((size_t)(b * CH + 4)) * 1024  + (size_t)tid * 4;

        const float4 o = *(const float4*)ptr;
        float v = -(__logf(1.f - o.x + EPSF) + __logf(1.f - o.y + EPSF) +
                    __logf(1.f - o.z + EPSF) + __logf(1.f - o.w + EPSF));

        #pragma unroll
        for (int off = 32; off > 0; off >>= 1)
            v += __shfl_xor(v, off, 64);

        __shared__ float redb[4];
        const int wave = tid >> 6;
        if ((tid & 63) == 0) redb[wave] = v;
        __syncthreads();
        if (tid == 0)
            parts_bg[blockIdx.x] = redb[0] + redb[1] + redb[2] + redb[3];
        return;
    }

    // ======== fg part: threads 0..149 map to (level, g) ========
    const int b = blockIdx.x - nbg;

    __shared__ float lab[5 * NG];
    __shared__ int   cand[3 * NG];
    if (tid < 5 * NG) lab[tid] = labels[b * 5 * NG + tid];
    if (tid < 3 * NG) cand[tid] = -1;
    __syncthreads();

    const int lv = tid / NG;            // 0..2 for tid<150
    const int g  = tid % NG;

    int xm = -1, ym = -1, found = -1;
    float s = 0.f; int W = 0, HW = 0;
    if (tid < 150) {
        s = (float)(8 << lv);
        const float rr = 0.5f * s;
        W = 128 >> lv; HW = W * W;
        const float gx = lab[g * 5 + 0];
        const float gy = lab[g * 5 + 1];
        const int x0 = (int)floorf(gx / s);
        const int y0 = (int)floorf(gy / s);
        #pragma unroll
        for (int d = -1; d <= 1; ++d) {
            int xc = x0 + d;
            if (xc >= 0 && xc < W) {
                float cxc = ((float)xc + 0.5f) * s;
                if (cxc - (gx - rr) > 0.f && gx + rr - cxc > 0.f) xm = xc;
            }
            int yc = y0 + d;
            if (yc >= 0 && yc < W) {
                float cyc = ((float)yc + 0.5f) * s;
                if (cyc - (gy - rr) > 0.f && gy + rr - cyc > 0.f) ym = yc;
            }
        }
        if (xm >= 0 && ym >= 0) { found = ym * W + xm; cand[tid] = found; }
    }
    __syncthreads();

    // dedup: anchor matches the LOWEST GT index covering it (reference argmax-first)
    bool fg = (found >= 0);
    if (fg) {
        const int base = lv * NG;
        for (int gp = 0; gp < g; ++gp)
            if (cand[base + gp] == found) { fg = false; break; }
    }

    float vals[5] = {0.f, 0.f, 0.f, 0.f, 0.f};
    if (fg) {
        const float* inp = (lv == 0) ? in0 : (lv == 1) ? in1 : in2;
        const float* chp = inp + ((size_t)b * CH) * HW + found;
        const float obj = chp[4 * HW];
        // correction: replace bg term with fg obj term
        vals[0] = -1000.f * __logf(obj + EPSF) + __logf(1.f - obj + EPSF);
        float xp = (chp[0]  + (float)xm) * s;
        float yp = (chp[HW] + (float)ym) * s;
        vals[1] = fabsf((lab[g * 5 + 0] - xp) * (1.f / 1024.f));
        vals[2] = fabsf((lab[g * 5 + 1] - yp) * (1.f / 1024.f));
        vals[3] = fabsf(lab[g * 5 + 2] - chp[2 * HW]) * 10.f;
        vals[4] = fabsf(lab[g * 5 + 3] - chp[3 * HW]) * 10.f;
        const int ci = (int)lab[g * 5 + 4];
        float cls_sum = 0.f;
        #pragma unroll
        for (int c = 0; c < NCLS; ++c) {
            float pc  = chp[(5 + c) * HW];
            float lp  = fmaxf(__logf(pc), -100.f);
            float l1p = fmaxf(__logf(1.f - pc), -100.f);
            cls_sum += (c == ci) ? -lp : -l1p;
        }
        vals[0] += 500.f * cls_sum;
    }

    // block reduce 5 values
    #pragma unroll
    for (int k = 0; k < 5; ++k) {
        float v = vals[k];
        #pragma unroll
        for (int off = 32; off > 0; off >>= 1)
            v += __shfl_xor(v, off, 64);
        vals[k] = v;
    }
    __shared__ float red[4][5];
    const int wave = tid >> 6;
    if ((tid & 63) == 0) {
        #pragma unroll
        for (int k = 0; k < 5; ++k) red[wave][k] = vals[k];
    }
    __syncthreads();
    if (tid < 5)
        parts_fg[tid * B + b] = red[0][tid] + red[1][tid] + red[2][tid] + red[3][tid];
}

// ---------------- final reduce ----------------
__global__ __launch_bounds__(256) void dpsv_reduce_kernel(
    const float* __restrict__ parts_bg, const float* __restrict__ parts_fg,
    float* __restrict__ out, int nbg, int B)
{
    const int tid = threadIdx.x;
    float acc[5] = {0.f, 0.f, 0.f, 0.f, 0.f};
    for (int i = tid; i < nbg; i += 256) acc[0] += parts_bg[i];
    for (int i = tid; i < B;   i += 256) {
        #pragma unroll
        for (int k = 0; k < 5; ++k) acc[k] += parts_fg[k * B + i];
    }
    #pragma unroll
    for (int k = 0; k < 5; ++k) {
        float v = acc[k];
        #pragma unroll
        for (int off = 32; off > 0; off >>= 1)
            v += __shfl_xor(v, off, 64);
        acc[k] = v;
    }
    __shared__ float red[4][5];
    const int wave = tid >> 6;
    if ((tid & 63) == 0) {
        #pragma unroll
        for (int k = 0; k < 5; ++k) red[wave][k] = acc[k];
    }
    __syncthreads();
    if (tid == 0) {
        float t[5];
        #pragma unroll
        for (int k = 0; k < 5; ++k)
            t[k] = red[0][k] + red[1][k] + red[2][k] + red[3][k];
        out[0] = t[0] + 10000.f * (t[1] + t[2] + t[3] + t[4]);
        out[1] = t[1];
        out[2] = t[2];
        out[3] = t[3];
        out[4] = t[4];
    }
}

extern "C" void kernel_launch(void* const* d_in, const int* in_sizes, int n_in,
                              void* d_out, int out_size, void* d_ws, size_t ws_size,
                              hipStream_t stream) {
    const float* in0    = (const float*)d_in[0];
    const float* in1    = (const float*)d_in[1];
    const float* in2    = (const float*)d_in[2];
    const float* labels = (const float*)d_in[3];
    float* out = (float*)d_out;
    float* ws  = (float*)d_ws;

    const int B   = in_sizes[3] / (5 * NG);  // 32
    const int nbg = B * 21;                  // 672 bg partials
    float* parts_bg = ws;
    float* parts_fg = ws + nbg;              // 5*B floats

    dpsv_fused_kernel<<<nbg + B, 256, 0, stream>>>(in0, in1, in2, labels,
                                                   parts_bg, parts_fg, B);
    dpsv_reduce_kernel<<<1, 256, 0, stream>>>(parts_bg, parts_fg, out, nbg, B);
}